// Round 9
// baseline (168.244 us; speedup 1.0000x reference)
//
#include <hip/hip_runtime.h>

// Round 9: horizontal 2-quad pairing. One thread handles quads (i,jj),(i,jj+1).
// Rationale: rounds 2-8 pinned at 38-47us kernel regardless of structure, BW
// <=2.8 TB/s => memory-level-parallelism bound. Pairing doubles lines per
// load burst per wave while keeping 1151 blocks (4.5/CU). Quad b's vertical
// edge reuses quad a's t2/r2 registers; vertex/vert rows load as contiguous
// multi-float4 spans shared by both quads.
//
// Energy collapse (verified absmax==0 rounds 1-8):
//   sum_pq coeff[p][q](Dp.Dq) = 3(|u|^2+|w|^2+u.w) + (|a|^2+|b|^2+a.b),
//   a = n1.(R1-R2), b = n2.(R1-R2), H=1.
// Adjacency (verified): quad (i,j), f1=tri1=i*m+j, tri2=Q+i*m+j.
//   diag : f2=tri2(i,j):   u=t1r2-t2r2, w=t1r1-t2r0; n1=N[v01], n2=N[v10]
//   horiz: f2=tri2(i-1,j): u=t1r0-t2r0, w=t1r2-t2r1; n1=N[v00], n2=N[v01]
//   vert : f2=tri2(i,j-1): u=t1r0-t2r2, w=t1r1-t2r1; n1=N[v00], n2=N[v10]
// Tail (jj==m-1, odd m): quad b invalid; loads base-clamped in-bounds, data
// re-selected via `tl` flag; clamp garbage only feeds masked edges (audited).

struct __attribute__((aligned(4))) F4s { float a, b, c, d; };
struct F3 { float x, y, z; };
struct R8  { float v[8];  };
struct R9  { float v[9];  };
struct R12 { float v[12]; };
struct R16 { float v[16]; };
struct R18 { float v[18]; };
struct R27 { float v[27]; };

__device__ __forceinline__ void ld4(const float* p, float* d) {
    F4s u = *(const F4s*)p; d[0]=u.a; d[1]=u.b; d[2]=u.c; d[3]=u.d;
}
__device__ __forceinline__ R8 load8(const float* p) {
    R8 r; ld4(p, r.v); ld4(p + 4, r.v + 4); return r;
}
__device__ __forceinline__ R9 load9(const float* p) {
    R9 r; ld4(p, r.v); ld4(p + 4, r.v + 4); r.v[8] = p[8]; return r;
}
__device__ __forceinline__ R12 load12(const float* p) {
    R12 r; ld4(p, r.v); ld4(p + 4, r.v + 4); ld4(p + 8, r.v + 8); return r;
}
__device__ __forceinline__ R16 load16(const float* p) {
    R16 r; ld4(p, r.v); ld4(p+4, r.v+4); ld4(p+8, r.v+8); ld4(p+12, r.v+12);
    return r;
}
__device__ __forceinline__ R18 load18(const float* p) {
    R18 r; ld4(p, r.v); ld4(p+4, r.v+4); ld4(p+8, r.v+8); ld4(p+12, r.v+12);
    float t[4]; ld4(p + 14, t); r.v[16] = t[2]; r.v[17] = t[3]; return r;
}
__device__ __forceinline__ R27 load27(const float* p) {
    R27 r; ld4(p, r.v); ld4(p+4, r.v+4); ld4(p+8, r.v+8); ld4(p+12, r.v+12);
    ld4(p+16, r.v+16); ld4(p+20, r.v+20);
    float t[4]; ld4(p + 23, t); r.v[24] = t[1]; r.v[25] = t[2]; r.v[26] = t[3];
    return r;
}

__device__ __forceinline__ int imin(int a, int b) { return a < b ? a : b; }
__device__ __forceinline__ int imax(int a, int b) { return a > b ? a : b; }

__device__ __forceinline__ F3 f3sel(bool t, const float* a, const float* b) {
    F3 r; r.x = t ? a[0] : b[0]; r.y = t ? a[1] : b[1]; r.z = t ? a[2] : b[2];
    return r;
}
__device__ __forceinline__ F3 f3of(const float* p) {
    F3 r; r.x = p[0]; r.y = p[1]; r.z = p[2]; return r;
}

__device__ __forceinline__ F3 normal9(const float* r) {
    float e1x = r[0] - r[3], e1y = r[1] - r[4], e1z = r[2] - r[5];
    float e2x = r[0] - r[6], e2y = r[1] - r[7], e2z = r[2] - r[8];
    float nx = e1y * e2z - e1z * e2y;
    float ny = e1z * e2x - e1x * e2z;
    float nz = e1x * e2y - e1y * e2x;
    float inv = 1.0f / sqrtf(nx * nx + ny * ny + nz * nz);
    F3 o; o.x = nx * inv; o.y = ny * inv; o.z = nz * inv; return o;
}

__device__ __forceinline__ float tri_area(const F3& p, const F3& q, const F3& r) {
    float ax = q.x - p.x, ay = q.y - p.y, az = q.z - p.z;
    float bx = r.x - p.x, by = r.y - p.y, bz = r.z - p.z;
    float cx = ay * bz - az * by, cy = az * bx - ax * bz, cz = ax * by - ay * bx;
    return 0.5f * sqrtf(cx * cx + cy * cy + cz * cz);
}

__device__ __forceinline__ float edge_ew(const float* u1, const float* u2,
                                         const float* w1, const float* w2,
                                         const float* rA, const float* rB,
                                         const F3& n1, const F3& n2,
                                         const F3& pa, const F3& pb,
                                         float asum) {
    float ux = u1[0] - u2[0], uy = u1[1] - u2[1], uz = u1[2] - u2[2];
    float wx = w1[0] - w2[0], wy = w1[1] - w2[1], wz = w1[2] - w2[2];

    float d0 = rA[0] - rB[0], d1 = rA[1] - rB[1], d2 = rA[2] - rB[2];
    float d3 = rA[3] - rB[3], d4 = rA[4] - rB[4], d5 = rA[5] - rB[5];
    float d6 = rA[6] - rB[6], d7 = rA[7] - rB[7], d8 = rA[8] - rB[8];

    float ax = n1.x * d0 + n1.y * d3 + n1.z * d6;
    float ay = n1.x * d1 + n1.y * d4 + n1.z * d7;
    float az = n1.x * d2 + n1.y * d5 + n1.z * d8;
    float bx = n2.x * d0 + n2.y * d3 + n2.z * d6;
    float by = n2.x * d1 + n2.y * d4 + n2.z * d7;
    float bz = n2.x * d2 + n2.y * d5 + n2.z * d8;

    float uu = ux * ux + uy * uy + uz * uz;
    float ww = wx * wx + wy * wy + wz * wz;
    float uw = ux * wx + uy * wy + uz * wz;
    float aa = ax * ax + ay * ay + az * az;
    float bb = bx * bx + by * by + bz * bz;
    float ab = ax * bx + ay * by + az * bz;
    float energy = (3.0f * (uu + ww + uw) + (aa + bb + ab)) * (1.0f / 9.0f);

    float dx = pa.x - pb.x, dy = pa.y - pb.y, dz = pa.z - pb.z;
    return energy * (dx * dx + dy * dy + dz * dz) / asum;
}

__global__ __launch_bounds__(256) void fused_kernel(
        const float* __restrict__ tp,    // (2Q,3,3)
        const float* __restrict__ rot,   // (2Q,3,3)
        const float* __restrict__ verts, // (n*n,3)
        double* __restrict__ partials,
        int n, int ppr) {
    const int m = n - 1;
    const int Q = m * m;
    const int tid = threadIdx.x;
    int p = blockIdx.x * 256 + tid;
    int i = p / ppr;
    int pj = p - i * ppr;
    int jj = 2 * pj;
    bool vi = (i < m);
    int ic = imin(i, m - 1);
    bool vb = vi && (jj + 1 < m);
    bool tl = (jj == m - 1);          // tail column (odd m): quad b invalid
    int vbq = vb ? 1 : 0;

    // ---- addresses ----
    int iu = imax(ic - 1, 0);
    int jl = imax(jj - 1, 0);
    size_t f1 = (size_t)ic * m + jj;
    size_t f2 = (size_t)Q + f1;
    size_t fu = (size_t)Q + (size_t)iu * m + jj;
    size_t fl = (size_t)Q + (size_t)ic * m + jl;
    int b2 = imin(jj, n - 3);         // vertex-row base col (rows i, i+1)
    int b3 = imin(jj - 1, n - 4);     // verts row i+1 base col (jj-1 clamped)
    int b4 = imin(jj + 1, n - 2);     // pup base col

    // ---- vertex-group loads (consumed first) ----
    R27 VA = load27(tp + (size_t)9 * ((size_t)ic * n + b2));        // tp rows of verts (i, b2..b2+2)
    R27 VC = load27(tp + (size_t)9 * ((size_t)(ic + 1) * n + b2));  // (i+1, b2..b2+2)
    R9  VI = load9(verts + (size_t)3 * ((size_t)ic * n + b2));      // verts (i, b2..b2+2)
    R12 VJ = load12(verts + 3 * ((size_t)(ic + 1) * n + b3));       // (i+1, b3..b3+3)
    R8  G  = load8(verts + (size_t)3 * ((size_t)iu * n + b4));      // (i-1, b4..b4+1)(+2f)

    // ---- face-group loads (consumed second; in flight during vertex math) ----
    R18 T1 = load18(tp  + 9 * f1);                 // tri1(i,jj), tri1(i,jj+1)
    R18 R1 = load18(rot + 9 * f1);
    R9  T2a = load9(tp  + 9 * f2);                 // tri2(i,jj)
    R9  R2a = load9(rot + 9 * f2);
    R9  T2b = load9(tp  + 9 * (f2 + vbq));         // tri2(i,jj+1) (dup if !vb)
    R9  R2b = load9(rot + 9 * (f2 + vbq));
    R16 TH = load16(tp  + 9 * fu);                 // tri2(i-1,jj) r0..1, (i-1,jj+1) r0..1
    R18 RH = load18(rot + 9 * fu);
    R8  TVL = load8(tp  + 9 * fl + 3);             // tri2(i,jj-1) rows 1,2
    R9  RVL = load9(rot + 9 * fl);

    // ---- consume vertex group: normals + positions + areas ----
    F3 N0 = normal9(VA.v + 0), N1 = normal9(VA.v + 9), N2 = normal9(VA.v + 18);
    F3 M0 = normal9(VC.v + 0), M1 = normal9(VC.v + 9), M2 = normal9(VC.v + 18);
    F3 nAa = f3sel(tl, VA.v + 9, VA.v + 0);  // placeholder; real sel below on normals
    // (select on computed normals, not raw rows)
    nAa = tl ? N1 : N0;
    F3 nBa = tl ? N2 : N1;
    F3 nBb = N2;
    F3 nAb = nBa;
    F3 nCa = tl ? M1 : M0;
    F3 nCb = tl ? M2 : M1;

    F3 p00a = f3sel(tl, VI.v + 3, VI.v + 0);
    F3 p01a = f3sel(tl, VI.v + 6, VI.v + 3);
    F3 p00b = p01a;
    F3 p01b = f3of(VI.v + 6);
    F3 plfa = f3sel(tl, VJ.v + 3, VJ.v + 0);
    F3 p10a = f3sel(tl, VJ.v + 6, VJ.v + 3);
    F3 p11a = f3sel(tl, VJ.v + 9, VJ.v + 6);
    F3 p10b = p11a;
    F3 p11b = f3of(VJ.v + 9);
    F3 pupa = f3sel(tl, G.v + 3, G.v + 0);
    F3 pupb = f3of(G.v + 3);

    float a1a  = tri_area(p00a, p10a, p01a);
    float a2ca = tri_area(p10a, p11a, p01a);
    float a2ua = tri_area(p00a, p01a, pupa);
    float a2la = tri_area(plfa, p10a, p00a);
    float a1b  = tri_area(p00b, p10b, p01b);
    float a2cb = tri_area(p10b, p11b, p01b);
    float a2ub = tri_area(p00b, p01b, pupb);

    // ---- consume face group: 6 edges ----
    float ea_d = edge_ew(T1.v + 6, T2a.v + 6, T1.v + 3, T2a.v + 0,
                         R1.v + 0, R2a.v, nBa, nCa, p01a, p10a, a1a + a2ca);
    float ea_h = edge_ew(T1.v + 0, TH.v + 0, T1.v + 6, TH.v + 3,
                         R1.v + 0, RH.v + 0, nAa, nBa, p00a, p01a, a1a + a2ua);
    float ea_v = edge_ew(T1.v + 0, TVL.v + 3, T1.v + 3, TVL.v + 0,
                         R1.v + 0, RVL.v, nAa, nCa, p00a, p10a, a1a + a2la);
    float eb_d = edge_ew(T1.v + 15, T2b.v + 6, T1.v + 12, T2b.v + 0,
                         R1.v + 9, R2b.v, nBb, nCb, p01b, p10b, a1b + a2cb);
    float eb_h = edge_ew(T1.v + 9, TH.v + 9, T1.v + 15, TH.v + 12,
                         R1.v + 9, RH.v + 9, nAb, nBb, p00b, p01b, a1b + a2ub);
    float eb_v = edge_ew(T1.v + 9, T2a.v + 6, T1.v + 12, T2a.v + 3,
                         R1.v + 9, R2a.v, nAb, nCb, p00b, p10b, a1b + a2ca);

    float sa = ea_d + (i > 0 ? ea_h : 0.0f) + (jj > 0 ? ea_v : 0.0f);
    float sb = eb_d + (i > 0 ? eb_h : 0.0f) + eb_v;   // jj+1>0 always
    double term = (vi ? (double)sa : 0.0) + (vb ? (double)sb : 0.0);

    // ---- block reduction ----
#pragma unroll
    for (int off = 32; off > 0; off >>= 1) term += __shfl_down(term, off, 64);
    __shared__ double sred[4];
    int lane = tid & 63, wid = tid >> 6;
    if (lane == 0) sred[wid] = term;
    __syncthreads();
    if (tid == 0)
        partials[blockIdx.x] = sred[0] + sred[1] + sred[2] + sred[3];
}

__global__ __launch_bounds__(256) void finalize_kernel(
        const double* __restrict__ partials, int P, float* __restrict__ out) {
    double s = 0.0;
    for (int i = threadIdx.x; i < P; i += 256) s += partials[i];
#pragma unroll
    for (int off = 32; off > 0; off >>= 1) s += __shfl_down(s, off, 64);
    __shared__ double sred[4];
    int lane = threadIdx.x & 63, wid = threadIdx.x >> 6;
    if (lane == 0) sred[wid] = s;
    __syncthreads();
    if (threadIdx.x == 0) out[0] = (float)(sred[0] + sred[1] + sred[2] + sred[3]);
}

extern "C" void kernel_launch(void* const* d_in, const int* in_sizes, int n_in,
                              void* d_out, int out_size, void* d_ws, size_t ws_size,
                              hipStream_t stream) {
    const float* tp    = (const float*)d_in[0];
    const float* rot   = (const float*)d_in[1];
    const float* verts = (const float*)d_in[2];

    int V = in_sizes[2] / 3;
    int n = (int)(sqrtf((float)V) + 0.5f);
    int m = n - 1;
    int ppr = (m + 1) / 2;

    double* partials = (double*)d_ws;
    float*  out      = (float*)d_out;

    int P = ((size_t)m * ppr + 255) / 256;
    fused_kernel<<<P, 256, 0, stream>>>(tp, rot, verts, partials, n, ppr);
    finalize_kernel<<<1, 256, 0, stream>>>(partials, P, out);
}